// Round 9
// baseline (211.507 us; speedup 1.0000x reference)
//
#include <hip/hip_runtime.h>

#define STEPS 10

typedef float vf2 __attribute__((ext_vector_type(2)));
typedef float vf4 __attribute__((ext_vector_type(4)));

// 3 lanes per element-PAIR (48B = 3 x float4). Lane k of a triad owns 4 of
// the pair's 12 neuron slots: k=0 -> elemA n0..3; k=1 -> elemA n4,5 + elemB
// n0,1; k=2 -> elemB n2..5. Lane 63 of each wave is a passenger.
// Requires B even (B = 500,000).
__global__ __launch_bounds__(256, 4) void spiking_vestibular_kernel(
    const float* __restrict__ speed,
    const float* __restrict__ turn_rate,
    const float* __restrict__ predicted_turn,
    const float* __restrict__ predicted_speed,
    const float* __restrict__ noise,
    const float* __restrict__ v0,
    const float* __restrict__ u0,
    const float* __restrict__ rate0,
    float* __restrict__ out,
    int B)
{
#pragma clang fp contract(off)
    const int wv = threadIdx.x >> 6;
    const int l  = threadIdx.x & 63;
    int q = l / 3;
    int k = l - 3 * q;
    const bool passenger = (l == 63);
    if (passenger) { q = 20; k = 0; }

    const long long P = (long long)(B >> 1);                 // pairs
    long long p = (long long)blockIdx.x * 84 + wv * 21 + q;  // 4 waves * 21 triads
    const bool valid = (p < P) && !passenger;
    if (p >= P) p = P - 1;

    const long long row = p * 12;       // float index of pair row (48B-aligned)
    const int ko = k * 4;

    // ---- ALL reads upfront; noise/state nontemporal dwordx4 ----
    vf4 nz[STEPS];
#pragma unroll
    for (int t = 0; t < STEPS; ++t)
        nz[t] = __builtin_nontemporal_load(
            reinterpret_cast<const vf4*>(noise + (long long)t * B * 6 + row + ko));
    vf4 vz = __builtin_nontemporal_load(reinterpret_cast<const vf4*>(v0    + row + ko));
    vf4 uz = __builtin_nontemporal_load(reinterpret_cast<const vf4*>(u0    + row + ko));
    vf4 rz = __builtin_nontemporal_load(reinterpret_cast<const vf4*>(rate0 + row + ko));
    vf2 tr2 = *reinterpret_cast<const vf2*>(turn_rate       + 2 * p);
    vf2 sp2 = *reinterpret_cast<const vf2*>(speed           + 2 * p);
    vf2 pt2 = *reinterpret_cast<const vf2*>(predicted_turn  + 2 * p);
    vf2 ps2 = *reinterpret_cast<const vf2*>(predicted_speed + 2 * p);

    __builtin_amdgcn_sched_barrier(0);

    const float trA = tr2.x, trB = tr2.y;
    const float spA = sp2.x, spB = sp2.y;
    const float ptA = pt2.x, ptB = pt2.y;
    const float psA = ps2.x, psB = ps2.y;

    const float tiltA = fminf(1.0f, (fabsf(trA) * spA) * 0.5f);
    const float tiltB = fminf(1.0f, (fabsf(trB) * spB) * 0.5f);

    // drive currents for this lane's 4 slots
    float I0, I1, I2, I3;
    if (k == 0) {            // elemA n0..3
        I0 = fmaxf(0.0f, trA) * 10.0f;
        I1 = fmaxf(0.0f, -trA) * 10.0f;
        I2 = spA * 5.0f;
        I3 = fmaxf(0.0f, -spA + 0.5f) * 5.0f;
    } else if (k == 1) {     // elemA n4,5 ; elemB n0,1
        I0 = tiltA * 8.0f;
        I1 = tiltA * 8.0f;
        I2 = fmaxf(0.0f, trB) * 10.0f;
        I3 = fmaxf(0.0f, -trB) * 10.0f;
    } else {                 // elemB n2..5
        I0 = spB * 5.0f;
        I1 = fmaxf(0.0f, -spB + 0.5f) * 5.0f;
        I2 = tiltB * 8.0f;
        I3 = tiltB * 8.0f;
    }

    float v0r = vz.x, v1r = vz.y, v2r = vz.z, v3r = vz.w;
    float u0r = uz.x, u1r = uz.y, u2r = uz.z, u3r = uz.w;
    float r0r = rz.x, r1r = rz.y, r2r = rz.z, r3r = rz.w;

#define IZH(Ix, vv_, uu_, rr_, nzc)                                            \
    {                                                                          \
        float i_tot = Ix + (nzc) * 0.3f + (-1.0f);                             \
        float vv = vv_, un = uu_;                                              \
        vv = vv + (((((0.04f * vv) * vv) + (5.0f * vv)) + 140.0f) - un + i_tot);\
        un = un + 0.02f * ((0.2f * vv) - un);                                  \
        bool fired = (vv >= 30.0f);                                            \
        float spk = fired ? 1.0f : 0.0f;                                       \
        vv = fired ? -65.0f : vv;                                              \
        un = un + spk * 8.0f;                                                  \
        rr_ = rr_ * 0.9f + spk * 0.1f;                                         \
        vv_ = vv; uu_ = un;                                                    \
    }

#pragma unroll
    for (int t = 0; t < STEPS; ++t) {
        IZH(I0, v0r, u0r, r0r, nz[t].x);
        IZH(I1, v1r, u1r, r1r, nz[t].y);
        IZH(I2, v2r, u2r, r2r, nz[t].z);
        IZH(I3, v3r, u3r, r3r, nz[t].w);
    }
#undef IZH

    // rate partial sums per element
    float s4 = ((r0r + r1r) + r2r) + r3r;
    float pA = (k == 0) ? s4 : (k == 1) ? (r0r + r1r) : 0.0f;
    float pB = (k == 2) ? s4 : (k == 1) ? (r2r + r3r) : 0.0f;
    float pA_n = __shfl(pA, l + 1, 64);
    float pB_n = __shfl(pB, l + 1, 64);
    float rateA = (pA + pA_n) / 6.0f;   // correct on lane k==0
    float rateB = (pB + pB_n) / 6.0f;   // correct on lane k==1

    // ---- TwoCompColumn relaxation for BOTH elements (cheap, redundant) ----
    float Ab0 = 0.0f, Ab1 = 0.0f, Aa0 = 0.0f, Aa1 = 0.0f;
    float Bb0 = 0.0f, Bb1 = 0.0f, Ba0 = 0.0f, Ba1 = 0.0f;
#pragma unroll
    for (int it = 0; it < 8; ++it) {
        Ab0 = Ab0 + 0.5f * (trA - Ab0);
        Ab1 = Ab1 + 0.5f * (spA - Ab1);
        Aa0 = Aa0 + 0.5f * (ptA - Aa0);
        Aa1 = Aa1 + 0.5f * (psA - Aa1);
        Bb0 = Bb0 + 0.5f * (trB - Bb0);
        Bb1 = Bb1 + 0.5f * (spB - Bb1);
        Ba0 = Ba0 + 0.5f * (ptB - Ba0);
        Ba1 = Ba1 + 0.5f * (psB - Ba1);
    }
    float peA0 = Ab0 - Aa0, peA1 = Ab1 - Aa1;
    float peB0 = Bb0 - Ba0, peB1 = Bb1 - Ba1;
    float prA0 = 1.0f / (1.0f + peA0 * peA0);
    float prA1 = 1.0f / (1.0f + peA1 * peA1);
    float prB0 = 1.0f / (1.0f + peB0 * peB0);
    float prB1 = 1.0f / (1.0f + peB1 * peB1);
    float feA = 0.5f * (((prA0 * peA0) * peA0) + ((prA1 * peA1) * peA1));
    float feB = 0.5f * (((prB0 * peB0) * peB0) + ((prB1 * peB1) * peB1));
    float pewA = 0.7f * peA0 + 0.3f * peA1;
    float pewB = 0.7f * peB0 + 0.3f * peB1;
    float pmA = (prA0 + prA1) / 2.0f;
    float pmB = (prB0 + prB1) / 2.0f;
    float postA = (-pmA) * pewA * 0.3f;
    float postB = (-pmB) * pewB * 0.3f;

    // per-k output quad: pair row = [tiltA,rateA,postA,pewA,pmA,feA, tiltB,...]
    vf4 o;
    if (k == 0)      { o.x = tiltA; o.y = rateA; o.z = postA; o.w = pewA; }
    else if (k == 1) { o.x = pmA;   o.y = feA;   o.z = tiltB; o.w = rateB; }
    else             { o.x = postB; o.y = pewB;  o.z = pmB;   o.w = feB; }

    if (valid)
        __builtin_nontemporal_store(o, reinterpret_cast<vf4*>(out + row + ko));
}

extern "C" void kernel_launch(void* const* d_in, const int* in_sizes, int n_in,
                              void* d_out, int out_size, void* d_ws, size_t ws_size,
                              hipStream_t stream) {
    // setup_inputs order:
    // 0 heading (unused), 1 speed, 2 turn_rate, 3 predicted_turn,
    // 4 predicted_speed, 5 noise [STEPS,B,N], 6 v0, 7 u0, 8 rate0
    const float* speed           = (const float*)d_in[1];
    const float* turn_rate       = (const float*)d_in[2];
    const float* predicted_turn  = (const float*)d_in[3];
    const float* predicted_speed = (const float*)d_in[4];
    const float* noise           = (const float*)d_in[5];
    const float* v0              = (const float*)d_in[6];
    const float* u0              = (const float*)d_in[7];
    const float* rate0           = (const float*)d_in[8];
    float* out                   = (float*)d_out;

    int B = in_sizes[1];
    long long pairs = (long long)(B >> 1);          // B is even (500,000)
    long long ppb = 84;                             // pairs per block (4 waves * 21)
    int grid = (int)((pairs + ppb - 1) / ppb);
    spiking_vestibular_kernel<<<grid, 256, 0, stream>>>(
        speed, turn_rate, predicted_turn, predicted_speed,
        noise, v0, u0, rate0, out, B);
}